// Round 1
// baseline (1558.074 us; speedup 1.0000x reference)
//
#include <hip/hip_runtime.h>
#include <cstdint>
#include <cstddef>

// Problem constants (match reference)
constexpr int B_  = 4;
constexpr int C_  = 256;
constexpr int H_  = 224;
constexpr int W_  = 224;
constexpr int PH_ = 7;
constexpr int PW_ = 7;
constexpr int P_  = 49;    // tokens per patch
constexpr int MH_ = 32;
constexpr int MW_ = 32;
constexpr int M_  = 1024;  // patches per image

constexpr int CPAD = 258;  // LDS row stride for [P][C] arrays (even -> float2 aligned; %32==2 -> 2-way max, free)
constexpr int SPAD = 50;   // LDS row stride for [P][P] arrays

// Output offsets (concatenated flat in reference return order)
constexpr size_t IMG_ELEMS = (size_t)B_ * C_ * H_ * W_;        // 51,380,224
constexpr size_t SCO_ELEMS = (size_t)B_ * M_ * P_ * P_;        //  9,834,496
constexpr size_t OFF_OUT = 0;
constexpr size_t OFF_SC  = OFF_OUT + IMG_ELEMS;
constexpr size_t OFF_COV = OFF_SC  + SCO_ELEMS;
constexpr size_t OFF_L   = OFF_COV + SCO_ELEMS;
constexpr size_t OFF_EC  = OFF_L   + SCO_ELEMS;

__global__ __launch_bounds__(256)
void psa_kernel(const float* __restrict__ x, const float* __restrict__ betap,
                float* __restrict__ out_img, float* __restrict__ out_sc,
                float* __restrict__ out_cov, float* __restrict__ out_l,
                float* __restrict__ out_ec)
{
    __shared__ float sA [P_ * CPAD];   // A[p][c]   (x values of this patch)
    __shared__ float sMc[P_ * CPAD];   // Mc, later Ec
    __shared__ float sS [P_ * SPAD];   // G -> Sc -> L (in place)
    __shared__ float colA[C_];         // per-channel mean of A over p
    __shared__ float colM[C_];         // per-channel mean of Mc over p
    __shared__ float red[P_];          // rowmax / inv rowsum

    const int tid = threadIdx.x;
    const int bm  = blockIdx.x;          // b*M + m
    const int b   = bm >> 10;            // / 1024
    const int m   = bm & (M_ - 1);
    const int mh  = m >> 5;
    const int mw  = m & (MW_ - 1);
    const float beta = betap[0];

    // base of element (c=0, i=0, j=0) of this patch in (B,C,H,W)
    const size_t xpatch = (((size_t)b * C_ * H_) + (size_t)mh * PH_) * W_ + (size_t)mw * PW_;

    // ---- Stage A[p][c] = x[b, c, mh*7+i, mw*7+j], p = i*7+j ----
    for (int r = tid; r < C_ * PH_; r += 256) {
        const int c = r / PH_;
        const int i = r - c * PH_;
        const float* src = x + xpatch + (size_t)c * (H_ * W_) + (size_t)i * W_;
        float* dst = &sA[(i * PW_) * CPAD + c];
        #pragma unroll
        for (int j = 0; j < PW_; ++j)
            dst[j * CPAD] = src[j];
    }
    __syncthreads();

    // ---- Column means of A (thread tid owns channel tid) ----
    {
        float s = 0.f;
        #pragma unroll
        for (int p = 0; p < P_; ++p) s += sA[p * CPAD + tid];
        colA[tid] = s * (1.f / 49.f);
    }
    // (colA consumed only after later barriers)

    // ---- G = A A^T  (49x49, each entry a 256-dot) ----
    for (int e = tid; e < P_ * P_; e += 256) {
        const int p = e / P_;
        const int q = e - p * P_;
        const float2* ap = (const float2*)&sA[p * CPAD];
        const float2* aq = (const float2*)&sA[q * CPAD];
        float acc0 = 0.f, acc1 = 0.f, acc2 = 0.f, acc3 = 0.f;
        #pragma unroll 8
        for (int c2 = 0; c2 < C_ / 2; c2 += 2) {
            float2 a0 = ap[c2], a1 = ap[c2 + 1];
            float2 b0 = aq[c2], b1 = aq[c2 + 1];
            acc0 += a0.x * b0.x; acc1 += a0.y * b0.y;
            acc2 += a1.x * b1.x; acc3 += a1.y * b1.y;
        }
        sS[p * SPAD + q] = (acc0 + acc1) + (acc2 + acc3);
    }
    __syncthreads();

    // ---- Softmax over rows (with max subtraction: |G| can reach ~70) ----
    if (tid < P_) {
        float mx = -3.4e38f;
        #pragma unroll
        for (int q = 0; q < P_; ++q) mx = fmaxf(mx, sS[tid * SPAD + q]);
        red[tid] = mx;
    }
    __syncthreads();
    for (int e = tid; e < P_ * P_; e += 256) {
        const int p = e / P_;
        const int q = e - p * P_;
        sS[p * SPAD + q] = __expf(sS[p * SPAD + q] - red[p]);
    }
    __syncthreads();
    if (tid < P_) {
        float s = 0.f;
        #pragma unroll
        for (int q = 0; q < P_; ++q) s += sS[tid * SPAD + q];
        red[tid] = 1.f / s;
    }
    __syncthreads();
    {
        float* sc_g = out_sc + (size_t)bm * (P_ * P_);
        for (int e = tid; e < P_ * P_; e += 256) {
            const int p = e / P_;
            const int q = e - p * P_;
            const float v = sS[p * SPAD + q] * red[p];
            sS[p * SPAD + q] = v;
            sc_g[e] = v;
        }
    }
    __syncthreads();

    // ---- Mc = Sc A  (49x256; iteration k computes row k, thread tid = channel) ----
    for (int k = 0; k < P_; ++k) {
        const float* srow = &sS[k * SPAD];
        float a0 = 0.f, a1 = 0.f, a2 = 0.f, a3 = 0.f;
        #pragma unroll
        for (int q = 0; q < 48; q += 4) {
            a0 += srow[q]     * sA[(q    ) * CPAD + tid];
            a1 += srow[q + 1] * sA[(q + 1) * CPAD + tid];
            a2 += srow[q + 2] * sA[(q + 2) * CPAD + tid];
            a3 += srow[q + 3] * sA[(q + 3) * CPAD + tid];
        }
        a0 += srow[48] * sA[48 * CPAD + tid];
        sMc[k * CPAD + tid] = (a0 + a1) + (a2 + a3);
    }
    __syncthreads();

    // ---- Column means of Mc ----
    {
        float s = 0.f;
        #pragma unroll
        for (int p = 0; p < P_; ++p) s += sMc[p * CPAD + tid];
        colM[tid] = s * (1.f / 49.f);
    }
    __syncthreads();

    // ---- cov = Ac Mcc^T / 49 ; L = Sc + cov (in place in sS) ----
    {
        float* cov_g = out_cov + (size_t)bm * (P_ * P_);
        float* l_g   = out_l   + (size_t)bm * (P_ * P_);
        const float2* ma = (const float2*)colA;
        const float2* mm = (const float2*)colM;
        for (int e = tid; e < P_ * P_; e += 256) {
            const int p = e / P_;
            const int q = e - p * P_;
            const float2* ap = (const float2*)&sA[p * CPAD];
            const float2* mq = (const float2*)&sMc[q * CPAD];
            float acc0 = 0.f, acc1 = 0.f;
            #pragma unroll 8
            for (int c2 = 0; c2 < C_ / 2; ++c2) {
                float2 av = ap[c2], mv = mq[c2], mav = ma[c2], mmv = mm[c2];
                acc0 += (av.x - mav.x) * (mv.x - mmv.x);
                acc1 += (av.y - mav.y) * (mv.y - mmv.y);
            }
            const float cv = (acc0 + acc1) * (1.f / 49.f);
            const float lv = sS[p * SPAD + q] + cv;
            cov_g[e] = cv;
            l_g[e]   = lv;
            sS[p * SPAD + q] = lv;
        }
    }
    __syncthreads();

    // ---- Ec = L A  (overwrite sMc) ----
    for (int k = 0; k < P_; ++k) {
        const float* lrow = &sS[k * SPAD];
        float a0 = 0.f, a1 = 0.f, a2 = 0.f, a3 = 0.f;
        #pragma unroll
        for (int q = 0; q < 48; q += 4) {
            a0 += lrow[q]     * sA[(q    ) * CPAD + tid];
            a1 += lrow[q + 1] * sA[(q + 1) * CPAD + tid];
            a2 += lrow[q + 2] * sA[(q + 2) * CPAD + tid];
            a3 += lrow[q + 3] * sA[(q + 3) * CPAD + tid];
        }
        a0 += lrow[48] * sA[48 * CPAD + tid];
        sMc[k * CPAD + tid] = (a0 + a1) + (a2 + a3);
    }
    __syncthreads();

    // ---- Fold back + elementwise: out = x*(beta*Ec + x); also write Ec_map ----
    for (int r = tid; r < C_ * PH_; r += 256) {
        const int c = r / PH_;
        const int i = r - c * PH_;
        const size_t gb = xpatch + (size_t)c * (H_ * W_) + (size_t)i * W_;
        #pragma unroll
        for (int j = 0; j < PW_; ++j) {
            const int p = i * PW_ + j;
            const float ec = sMc[p * CPAD + c];
            const float xv = sA[p * CPAD + c];
            out_ec[gb + j]  = ec;
            out_img[gb + j] = xv * (beta * ec + xv);
        }
    }
}

extern "C" void kernel_launch(void* const* d_in, const int* in_sizes, int n_in,
                              void* d_out, int out_size, void* d_ws, size_t ws_size,
                              hipStream_t stream) {
    const float* x    = (const float*)d_in[0];
    const float* beta = (const float*)d_in[1];
    // d_in[2], d_in[3] are ph, pw (ints) — hardcoded to 7.

    float* out = (float*)d_out;
    psa_kernel<<<dim3(B_ * M_), dim3(256), 0, stream>>>(
        x, beta,
        out + OFF_OUT,
        out + OFF_SC,
        out + OFF_COV,
        out + OFF_L,
        out + OFF_EC);
}

// Round 2
// 547.288 us; speedup vs baseline: 2.8469x; 2.8469x over previous
//
#include <hip/hip_runtime.h>
#include <cstdint>
#include <cstddef>

// Problem constants
constexpr int C_  = 256;
constexpr int H_  = 224;
constexpr int W_  = 224;
constexpr int P_  = 49;
constexpr int M_  = 1024;
constexpr int HW_ = H_ * W_;

constexpr int CPAD = 258;  // sA row stride (floats)
constexpr int SPAD = 50;   // 49x49 row stride
constexpr int TPAD = 66;   // transpose-staging row stride (64 cols + pad)

constexpr size_t IMG_ELEMS = (size_t)4 * C_ * H_ * W_;   // 51,380,224
constexpr size_t SCO_ELEMS = (size_t)4 * M_ * P_ * P_;   //  9,834,496
constexpr size_t OFF_SC  = IMG_ELEMS;
constexpr size_t OFF_COV = OFF_SC  + SCO_ELEMS;
constexpr size_t OFF_L   = OFF_COV + SCO_ELEMS;
constexpr size_t OFF_EC  = OFF_L   + SCO_ELEMS;

// Column swizzle for sA: c ^ (((p>>2)&3)<<1). Keeps float2 (even-c) contiguity.
// Bank math: word(p,c) = 258p + c^s2. Row-group reads (p in 4ty..4ty+3, same s2)
// land in 4 distinct banks; col-group reads (p = 4tx+j, tx 0..15) get bank
// separation from 8s + (c&6)^2s being distinct for s = tx&3 -> conflict-free.
__device__ __forceinline__ int swz(int p) { return (p >> 1) & 6; }

__global__ __launch_bounds__(256, 2)
void psa_kernel(const float* __restrict__ x, const float* __restrict__ betap,
                float* __restrict__ out_img, float* __restrict__ out_sc,
                float* __restrict__ out_cov, float* __restrict__ out_l,
                float* __restrict__ out_ec)
{
    __shared__ float sA [P_ * CPAD];   // A (x of this patch), swizzled columns
    __shared__ float sS [P_ * SPAD];   // exp -> Sc -> L (in place)
    __shared__ float sGT[P_ * TPAD];   // G (stride SPAD), later Ec-transpose T (stride TPAD)
    __shared__ float red[192];         // [0:49] rowmax / inv-rowsum, [64:113] u, [128:177] w

    const int tid = threadIdx.x;
    const int bid = blockIdx.x;
    // XCD-bijective swizzle (4096 % 8 == 0): contiguous patch ranges per XCD
    const int bm  = ((bid & 7) << 9) | (bid >> 3);
    const int b   = bm >> 10;
    const int m   = bm & (M_ - 1);
    const int mh  = m >> 5;
    const int mw  = m & 31;
    const float beta = betap[0];

    const size_t xpatch = (((size_t)b * C_ * H_) + (size_t)mh * 7) * W_ + (size_t)mw * 7;

    // ---- Stage A[p][c] (swizzled) ----
    for (int r = tid; r < C_ * 7; r += 256) {
        const int c = r / 7;
        const int i = r - c * 7;
        const float* src = x + xpatch + (size_t)c * HW_ + (size_t)i * W_;
        #pragma unroll
        for (int j = 0; j < 7; ++j) {
            const int p = i * 7 + j;
            sA[p * CPAD + (c ^ swz(p))] = src[j];
        }
    }
    __syncthreads();

    // ---- G = A A^T, 4x4 register tiles, symmetric (upper tiles only) ----
    const int tx = tid & 15, ty = tid >> 4;
    const int p0 = ty * 4, q0 = tx * 4;
    const bool gvalid = (p0 < P_) && (q0 < P_);          // ty,tx <= 12
    if (gvalid && tx >= ty) {
        const float* rowA = &sA[p0 * CPAD];
        const float* rowB = &sA[q0 * CPAD];
        const int sa = (ty & 3) * 2, sb = (tx & 3) * 2;
        float acc[4][4] = {};
        #pragma unroll 2
        for (int cc = 0; cc < C_; cc += 2) {
            const int ia = cc ^ sa, ib = cc ^ sb;
            float2 ra[4], rb[4];
            #pragma unroll
            for (int i = 0; i < 4; ++i) ra[i] = *(const float2*)&rowA[i * CPAD + ia];
            #pragma unroll
            for (int j = 0; j < 4; ++j) rb[j] = *(const float2*)&rowB[j * CPAD + ib];
            #pragma unroll
            for (int i = 0; i < 4; ++i)
                #pragma unroll
                for (int j = 0; j < 4; ++j)
                    acc[i][j] += ra[i].x * rb[j].x + ra[i].y * rb[j].y;
        }
        #pragma unroll
        for (int i = 0; i < 4; ++i) {
            if (p0 + i >= P_) break;
            #pragma unroll
            for (int j = 0; j < 4; ++j) {
                if (q0 + j >= P_) break;
                sGT[(p0 + i) * SPAD + (q0 + j)] = acc[i][j];
                if (tx > ty) sGT[(q0 + j) * SPAD + (p0 + i)] = acc[i][j];
            }
        }
    }
    __syncthreads();

    // ---- Softmax: rowmax ----
    if (tid < P_) {
        float mx = -3.4e38f;
        #pragma unroll
        for (int q = 0; q < P_; ++q) mx = fmaxf(mx, sGT[tid * SPAD + q]);
        red[tid] = mx;
    }
    __syncthreads();
    // exp (G stays intact in sGT; exp goes to sS)
    for (int e = tid; e < P_ * P_; e += 256) {
        const int p = e / P_;
        const int q = e - p * P_;
        sS[p * SPAD + q] = __expf(sGT[p * SPAD + q] - red[p]);
    }
    __syncthreads();
    if (tid < P_) {
        float s = 0.f;
        #pragma unroll
        for (int q = 0; q < P_; ++q) s += sS[tid * SPAD + q];
        red[tid] = 1.f / s;
    }
    __syncthreads();
    {
        float* sc_g = out_sc + (size_t)bm * (P_ * P_);
        for (int e = tid; e < P_ * P_; e += 256) {
            const int p = e / P_;
            const int q = e - p * P_;
            const float v = sS[p * SPAD + q] * red[p];
            sS[p * SPAD + q] = v;
            sc_g[e] = v;
        }
    }
    __syncthreads();

    // ---- u[r] = colmean(G), w[r] = colmean(Sc) ----
    if (tid < P_) {
        float su = 0.f, sw = 0.f;
        #pragma unroll 7
        for (int p = 0; p < P_; ++p) {
            su += sGT[p * SPAD + tid];
            sw += sS [p * SPAD + tid];
        }
        red[64  + tid] = su * (1.f / 49.f);
        red[128 + tid] = sw * (1.f / 49.f);
    }
    __syncthreads();

    // ---- cov[p][q] = (1/49) sum_r (Sc[q][r]-w[r]) * (G[p][r]-u[r]) ----
    float cv[4][4] = {};
    if (gvalid) {
        const float* gp_ = &sGT[p0 * SPAD];
        const float* sq_ = &sS [q0 * SPAD];
        for (int r = 0; r < P_; ++r) {
            const float uu = red[64 + r], ww = red[128 + r];
            float g[4], s[4];
            #pragma unroll
            for (int i = 0; i < 4; ++i) g[i] = gp_[i * SPAD + r] - uu;
            #pragma unroll
            for (int j = 0; j < 4; ++j) s[j] = sq_[j * SPAD + r] - ww;
            #pragma unroll
            for (int i = 0; i < 4; ++i)
                #pragma unroll
                for (int j = 0; j < 4; ++j)
                    cv[i][j] += g[i] * s[j];
        }
    }
    __syncthreads();
    // L = Sc + cov (overwrite sS); emit cov, L
    if (gvalid) {
        float* cov_g = out_cov + (size_t)bm * (P_ * P_);
        float* l_g   = out_l   + (size_t)bm * (P_ * P_);
        #pragma unroll
        for (int i = 0; i < 4; ++i) {
            const int p = p0 + i;
            if (p >= P_) break;
            #pragma unroll
            for (int j = 0; j < 4; ++j) {
                const int q = q0 + j;
                if (q >= P_) break;
                const float cvv = cv[i][j] * (1.f / 49.f);
                const float lv  = sS[p * SPAD + q] + cvv;   // own entry only: no race
                sS[p * SPAD + q] = lv;
                cov_g[p * P_ + q] = cvv;
                l_g  [p * P_ + q] = lv;
            }
        }
    }
    __syncthreads();

    // ---- Ec = L A, 64 columns per pass; transpose via sT; fold + outputs ----
    const int kg = tid >> 6, cl = tid & 63;
    const int kb = kg * 12;                 // k ranges [0,12],[12,24],[24,36],[36,48] (dup rows benign)
    float* sT = sGT;                        // G dead; reuse as T (stride TPAD)
    for (int cb = 0; cb < 4; ++cb) {
        const int c = cb * 64 + cl;
        float acc[13];
        #pragma unroll
        for (int kk = 0; kk < 13; ++kk) acc[kk] = 0.f;
        for (int q = 0; q < 48; q += 2) {
            const int s2 = swz(q);          // pairs (q,q+1) share the swizzle group
            const float a0 = sA[q       * CPAD + (c ^ s2)];
            const float a1 = sA[(q + 1) * CPAD + (c ^ s2)];
            #pragma unroll
            for (int kk = 0; kk < 13; ++kk) {
                const float2 lv = *(const float2*)&sS[(kb + kk) * SPAD + q];
                acc[kk] += lv.x * a0 + lv.y * a1;
            }
        }
        {   // tail q = 48 (swz(48) == 0)
            const float a0 = sA[48 * CPAD + c];
            #pragma unroll
            for (int kk = 0; kk < 13; ++kk)
                acc[kk] += sS[(kb + kk) * SPAD + 48] * a0;
        }
        #pragma unroll
        for (int kk = 0; kk < 13; ++kk)
            sT[(kb + kk) * TPAD + cl] = acc[kk];
        __syncthreads();

        // fold these 64 channels: 448 (c_local, i) pairs
        for (int pr = tid; pr < 448; pr += 256) {
            const int i   = pr >> 6;
            const int cl2 = pr & 63;
            const int c2  = cb * 64 + cl2;
            const size_t gb = xpatch + (size_t)c2 * HW_ + (size_t)i * W_;
            float* oimg = out_img + gb;
            float* oec  = out_ec  + gb;
            #pragma unroll
            for (int j = 0; j < 7; ++j) {
                const int p = i * 7 + j;
                const float ec = sT[p * TPAD + cl2];
                const float xv = sA[p * CPAD + (c2 ^ swz(p))];
                oec[j]  = ec;
                oimg[j] = xv * fmaf(beta, ec, xv);
            }
        }
        __syncthreads();
    }
}

extern "C" void kernel_launch(void* const* d_in, const int* in_sizes, int n_in,
                              void* d_out, int out_size, void* d_ws, size_t ws_size,
                              hipStream_t stream) {
    const float* x    = (const float*)d_in[0];
    const float* beta = (const float*)d_in[1];
    float* out = (float*)d_out;
    psa_kernel<<<dim3(4 * M_), dim3(256), 0, stream>>>(
        x, beta,
        out,
        out + OFF_SC,
        out + OFF_COV,
        out + OFF_L,
        out + OFF_EC);
}

// Round 3
// 370.900 us; speedup vs baseline: 4.2008x; 1.4756x over previous
//
#include <hip/hip_runtime.h>
#include <hip/hip_bf16.h>
#include <cstdint>
#include <cstddef>

constexpr int C_  = 256;
constexpr int H_  = 224;
constexpr int W_  = 224;
constexpr int P_  = 49;
constexpr int M_  = 1024;
constexpr int HW_ = H_ * W_;

constexpr size_t IMG_ELEMS = (size_t)4 * C_ * H_ * W_;
constexpr size_t SCO_ELEMS = (size_t)4 * M_ * P_ * P_;
constexpr size_t OFF_SC  = IMG_ELEMS;
constexpr size_t OFF_COV = OFF_SC  + SCO_ELEMS;
constexpr size_t OFF_L   = OFF_COV + SCO_ELEMS;
constexpr size_t OFF_EC  = OFF_L   + SCO_ELEMS;

typedef __attribute__((ext_vector_type(8))) short short8;
typedef __attribute__((ext_vector_type(4))) float f32x4;

// LDS layout (bytes):
//   sA  bf16 [49][264]  @ 0       (25,872)  -- G operands; dead after G -> overlays
//     Gb  bf16 [64][72] @ 0       ( 9,216)  -- cov A-operand; dead after cov -> Lb
//     Scc bf16 [64][72] @ 9,216   ( 9,216)  -- cov B-operand
//   sAT bf16 [256][72]  @ 25,872  (36,864)  -- Ec^T A-operand (cols 49..63 zeroed)
//   sG  f32  [49][52]   @ 62,736  (10,192)  -- G -> exp -> Sc (in place)
//   u   f32  [64]       @ 72,928
//   w   f32  [64]       @ 73,184
constexpr int SMEM_BYTES = 73472;

__global__ __launch_bounds__(256, 2)
void psa_kernel(const float* __restrict__ x, const float* __restrict__ betap,
                float* __restrict__ out_img, float* __restrict__ out_sc,
                float* __restrict__ out_cov, float* __restrict__ out_l,
                float* __restrict__ out_ec)
{
    __shared__ __align__(16) unsigned char smem[SMEM_BYTES];
    __hip_bfloat16* sA  = (__hip_bfloat16*)(smem);
    __hip_bfloat16* Gb  = (__hip_bfloat16*)(smem);            // overlay (after G)
    __hip_bfloat16* Scc = (__hip_bfloat16*)(smem + 9216);     // overlay (after G)
    __hip_bfloat16* Lb  = (__hip_bfloat16*)(smem);            // overlay (after cov)
    __hip_bfloat16* sAT = (__hip_bfloat16*)(smem + 25872);
    float* sG   = (float*)(smem + 62736);
    float* uArr = (float*)(smem + 72928);
    float* wArr = (float*)(smem + 73184);

    const int tid  = threadIdx.x;
    const int bid  = blockIdx.x;
    const int bm   = ((bid & 7) << 9) | (bid >> 3);   // XCD-bijective swizzle
    const int b    = bm >> 10;
    const int m    = bm & (M_ - 1);
    const int mh   = m >> 5;
    const int mw   = m & 31;
    const float beta = betap[0];

    const size_t xpatch = (((size_t)b * C_ * H_) + (size_t)mh * 7) * W_ + (size_t)mw * 7;

    const int wid  = tid >> 6;
    const int lane = tid & 63;
    const int l15  = lane & 15;
    const int lh   = lane >> 4;

    // ---- Stage: thread = channel; fill sA (row-major) and sAT (transposed + zero pad)
    {
        const int c = tid;
        const float* src = x + xpatch + (size_t)c * HW_;
        __hip_bfloat16 vals[49];
        #pragma unroll
        for (int i = 0; i < 7; ++i)
            #pragma unroll
            for (int j = 0; j < 7; ++j)
                vals[i * 7 + j] = __float2bfloat16(src[i * W_ + j]);
        #pragma unroll
        for (int p = 0; p < 49; ++p) sA[p * 264 + c] = vals[p];
        #pragma unroll
        for (int p = 0; p < 49; ++p) sAT[c * 72 + p] = vals[p];
        const __hip_bfloat16 z = __float2bfloat16(0.f);
        #pragma unroll
        for (int p = 49; p < 64; ++p) sAT[c * 72 + p] = z;
    }
    __syncthreads();

    // ---- G = A A^T via MFMA: wave wid owns rows p0=16*wid; 4 q-tiles; K=256
    {
        f32x4 acc[4] = {f32x4{0,0,0,0}, f32x4{0,0,0,0}, f32x4{0,0,0,0}, f32x4{0,0,0,0}};
        const int arow = 16 * wid + l15;   // rows 49..63 read stale finite bf16 -> discarded D rows
        #pragma unroll 2
        for (int kc = 0; kc < 8; ++kc) {
            const int cofs = kc * 32 + 8 * lh;
            const short8 af = *(const short8*)&sA[arow * 264 + cofs];
            #pragma unroll
            for (int t = 0; t < 4; ++t) {
                const short8 bf = *(const short8*)&sA[(16 * t + l15) * 264 + cofs];
                acc[t] = __builtin_amdgcn_mfma_f32_16x16x32_bf16(af, bf, acc[t], 0, 0, 0);
            }
        }
        #pragma unroll
        for (int t = 0; t < 4; ++t) {
            const int q = 16 * t + l15;
            if (q <= 48) {
                #pragma unroll
                for (int r = 0; r < 4; ++r) {
                    const int p = 16 * wid + 4 * lh + r;
                    if (p <= 48) sG[p * 52 + q] = acc[t][r];
                }
            }
        }
    }
    __syncthreads();

    // ---- rowmax + u (G symmetric: colmean == rowmean). 196 threads, 4 lanes/row.
    float rowmax_reg = 0.f;
    {
        if (tid < 196) {
            const int row = tid >> 2, s = tid & 3;
            const int qa = s * 13, qb = (qa + 13 < 49) ? qa + 13 : 49;
            float mx = -3.4e38f, sm = 0.f;
            for (int q = qa; q < qb; ++q) {
                const float v = sG[row * 52 + q];
                mx = fmaxf(mx, v); sm += v;
            }
            mx = fmaxf(mx, __shfl_xor(mx, 1));
            mx = fmaxf(mx, __shfl_xor(mx, 2));
            sm += __shfl_xor(sm, 1);
            sm += __shfl_xor(sm, 2);
            if (s == 0) uArr[row] = sm * (1.f / 49.f);
            rowmax_reg = mx;
        }
    }
    __syncthreads();

    // ---- Gb = bf16(G - u) (raw G still in sG), zero-padded cols 49..63
    for (int e = tid; e < 49 * 64; e += 256) {
        const int p = e >> 6, r = e & 63;
        const float v = (r <= 48) ? (sG[p * 52 + r] - uArr[r]) : 0.f;
        Gb[p * 72 + r] = __float2bfloat16(v);
    }
    __syncthreads();

    // ---- exp/sum/scale in place; write Sc to global
    {
        if (tid < 196) {
            const int row = tid >> 2, s = tid & 3;
            const int qa = s * 13, qb = (qa + 13 < 49) ? qa + 13 : 49;
            float sm = 0.f;
            for (int q = qa; q < qb; ++q) {
                const float ev = __expf(sG[row * 52 + q] - rowmax_reg);
                sG[row * 52 + q] = ev;
                sm += ev;
            }
            sm += __shfl_xor(sm, 1);
            sm += __shfl_xor(sm, 2);
            const float rinv = 1.f / sm;
            float* sc_g = out_sc + (size_t)bm * (P_ * P_) + row * 49;
            for (int q = qa; q < qb; ++q) {
                const float v = sG[row * 52 + q] * rinv;
                sG[row * 52 + q] = v;
                sc_g[q] = v;
            }
        }
    }
    __syncthreads();

    // ---- w = colmean(Sc) (not symmetric -> true column sums)
    {
        if (tid < 196) {
            const int r = tid >> 2, s = tid & 3;
            const int pa = s * 13, pb = (pa + 13 < 49) ? pa + 13 : 49;
            float sm = 0.f;
            for (int p = pa; p < pb; ++p) sm += sG[p * 52 + r];
            sm += __shfl_xor(sm, 1);
            sm += __shfl_xor(sm, 2);
            if (s == 0) wArr[r] = sm * (1.f / 49.f);
        }
    }
    __syncthreads();

    // ---- Scc = bf16(Sc - w), zero-padded cols 49..63
    for (int e = tid; e < 49 * 64; e += 256) {
        const int q = e >> 6, r = e & 63;
        const float v = (r <= 48) ? (sG[q * 52 + r] - wArr[r]) : 0.f;
        Scc[q * 72 + r] = __float2bfloat16(v);
    }
    __syncthreads();

    // ---- cov = (1/49) * Gb . Scc^T via MFMA (K=64); L = Sc + cov; Lb overlay
    {
        f32x4 acc[4] = {f32x4{0,0,0,0}, f32x4{0,0,0,0}, f32x4{0,0,0,0}, f32x4{0,0,0,0}};
        const int arow = 16 * wid + l15;
        #pragma unroll
        for (int kc = 0; kc < 2; ++kc) {
            const int cofs = kc * 32 + 8 * lh;
            const short8 af = *(const short8*)&Gb[arow * 72 + cofs];
            #pragma unroll
            for (int t = 0; t < 4; ++t) {
                const short8 bf = *(const short8*)&Scc[(16 * t + l15) * 72 + cofs];
                acc[t] = __builtin_amdgcn_mfma_f32_16x16x32_bf16(af, bf, acc[t], 0, 0, 0);
            }
        }
        __syncthreads();   // all cov MFMAs done before Lb overwrites Gb

        float* cov_g = out_cov + (size_t)bm * (P_ * P_);
        float* l_g   = out_l   + (size_t)bm * (P_ * P_);
        #pragma unroll
        for (int t = 0; t < 4; ++t) {
            const int q = 16 * t + l15;
            #pragma unroll
            for (int r = 0; r < 4; ++r) {
                const int p = 16 * wid + 4 * lh + r;
                if (p <= 48 && q <= 48) {
                    const float cv = acc[t][r] * (1.f / 49.f);
                    const float lv = sG[p * 52 + q] + cv;
                    cov_g[p * 49 + q] = cv;
                    l_g  [p * 49 + q] = lv;
                    Lb[p * 72 + q] = __float2bfloat16(lv);   // cols 49..63 remain Gb's zeros
                }
            }
        }
    }
    __syncthreads();

    // ---- Ec^T = A^T . L^T via MFMA: wave wid owns channels c in [64*wid, 64*wid+64)
    {
        f32x4 acc[16];
        #pragma unroll
        for (int i = 0; i < 16; ++i) acc[i] = f32x4{0, 0, 0, 0};
        #pragma unroll
        for (int kc = 0; kc < 2; ++kc) {
            const int cofs = kc * 32 + 8 * lh;
            short8 af[4], bf[4];
            #pragma unroll
            for (int ct = 0; ct < 4; ++ct)
                af[ct] = *(const short8*)&sAT[(64 * wid + 16 * ct + l15) * 72 + cofs];
            #pragma unroll
            for (int pt = 0; pt < 4; ++pt)
                bf[pt] = *(const short8*)&Lb[(16 * pt + l15) * 72 + cofs];
            #pragma unroll
            for (int ct = 0; ct < 4; ++ct)
                #pragma unroll
                for (int pt = 0; pt < 4; ++pt)
                    acc[ct * 4 + pt] = __builtin_amdgcn_mfma_f32_16x16x32_bf16(
                        af[ct], bf[pt], acc[ct * 4 + pt], 0, 0, 0);
        }

        // Epilogue: D[c][p]; lane holds col p = 16*pt + l15, rows c = 64*wid+16*ct+4*lh+r
        #pragma unroll
        for (int pt = 0; pt < 4; ++pt) {
            const int p = 16 * pt + l15;
            if (p > 48) continue;
            const int i = p / 7, j = p % 7;
            const size_t base = xpatch + (size_t)i * W_ + j;
            #pragma unroll
            for (int ct = 0; ct < 4; ++ct) {
                #pragma unroll
                for (int r = 0; r < 4; ++r) {
                    const int c = 64 * wid + 16 * ct + 4 * lh + r;
                    const size_t g = base + (size_t)c * HW_;
                    const float ec = acc[ct * 4 + pt][r];
                    const float xv = x[g];
                    out_ec [g] = ec;
                    out_img[g] = xv * fmaf(beta, ec, xv);
                }
            }
        }
    }
}

extern "C" void kernel_launch(void* const* d_in, const int* in_sizes, int n_in,
                              void* d_out, int out_size, void* d_ws, size_t ws_size,
                              hipStream_t stream) {
    const float* x    = (const float*)d_in[0];
    const float* beta = (const float*)d_in[1];
    float* out = (float*)d_out;
    psa_kernel<<<dim3(4 * M_), dim3(256), 0, stream>>>(
        x, beta,
        out,
        out + OFF_SC,
        out + OFF_COV,
        out + OFF_L,
        out + OFF_EC);
}